// Round 11
// baseline (1184.882 us; speedup 1.0000x reference)
//
#include <hip/hip_runtime.h>
#include <hip/hip_bf16.h>

typedef __bf16 bf16x4 __attribute__((ext_vector_type(4)));
typedef __bf16 bf16x8 __attribute__((ext_vector_type(8)));
typedef float  floatx4 __attribute__((ext_vector_type(4)));

#define AS1 __attribute__((address_space(1)))
#define AS3 __attribute__((address_space(3)))

#define BM2 256
#define BN2 256
#define BK2 64
#define HALF (128 * 64)      // elems per half-tile (128 rows x 64 cols)
#define ABUF (2 * HALF)      // elems per double-buffer slot

#define BARRIER() asm volatile("s_barrier" ::: "memory")

// ---------------------------------------------------------------------------
// GEMM v13 — FUSED conversions (prepass deleted). v12's schedule skeleton
// (260us plateau, best measured) with staging switched from gload_lds to
// reg-staging that converts in flight:
//   A: fp32 -> bf16, W: int32 -> bf16, written to the SAME swizzled LDS
//   image as before (LDS[row][blk16B] = G[row][blk^(row&7)]) -> fragment
//   reads / MFMA / epilogue identical to v12.
// Why: total = 180us fixed overhead + ~65us cvt pass + 263us GEMM; GEMM is
// at its schedule plateau (v7/v9/v12 all 260+-3, 45-46% MfmaUtil), but the
// cvt pass is eliminable: measured idle is ~1900 cyc/SIMD/tile and the
// conversion work (~500 cyc/SIMD/tile) hides in it.
// Staging pipeline per tile kt (buf c), chunks c0..c3 =
//   {A(kt+1)h0, A(kt+1)h1, B(kt+2)h0, B(kt+2)h1}:
//   P1: issue c0->s0 | post: write prev-c3 (s1) -> sB[c^1] h1
//   P2: issue c1->s1 | post: write c0 (s0) -> sA[c^1] h0
//   P3: issue c2->s0 | post: write c1 (s1) -> sA[c^1] h1
//   P4: issue c3->s1 | post: bfA read; write c2 (s0) -> sB[c] h0
// No manual vmcnt (compiler tracks load->reg deps; auto-inserts counted
// waits). Visibility: lgkmcnt(0) + barrier per phase end. Liveness verified:
// every written region's readers completed >=2 barriers earlier; phantom
// tail writes land in dead buffers. Prologue stages A(0),B(0),B(1)h0
// synchronously and leaves B(1)h1 pending in s1 = exactly steady state.
// Per-thread unit map (512 thr): u = tid + j*512 (j=0..3), row=u>>4,
// cb=u&15; global elem off = (h*128+row)*K + kt*64 + cb*4 (both dtypes 4B);
// LDS byte = base + row*128 + ((cb>>1)^(row&7))*16 + (cb&1)*8  -> same
// image as gload_lds era; write pattern covers 32 banks exactly 4x/wave
// (conflict-free).
// ---------------------------------------------------------------------------
template<int Q>
__device__ __forceinline__ void mfma16s(floatx4 (&acc)[8][4],
                                        const bf16x8 (&af)[2][2],
                                        const bf16x8 (&bfA)[2][2],
                                        const bf16x8 (&bfB)[2][2])
{
#pragma unroll
    for (int h = 0; h < 2; ++h)
#pragma unroll
        for (int ii = 0; ii < 2; ++ii) {
#pragma unroll
            for (int j = 0; j < 2; ++j)
                acc[2 * Q + ii][j] = __builtin_amdgcn_mfma_f32_16x16x32_bf16(
                    af[ii][h], bfA[j][h], acc[2 * Q + ii][j], 0, 0, 0);
#pragma unroll
            for (int j = 0; j < 2; ++j)
                acc[2 * Q + ii][2 + j] = __builtin_amdgcn_mfma_f32_16x16x32_bf16(
                    af[ii][h], bfB[j][h], acc[2 * Q + ii][2 + j], 0, 0, 0);
        }
}

__device__ __forceinline__ void read_afH(bf16x8 (&dst)[2][2], const __bf16* p,
                                         int rowBase, int lm, int kq, int sw)
{
#pragma unroll
    for (int ii = 0; ii < 2; ++ii)
#pragma unroll
        for (int h = 0; h < 2; ++h)
            dst[ii][h] = *reinterpret_cast<const bf16x8*>(
                &p[(rowBase + ii * 16 + lm) * BK2 + ((kq + h * 4) ^ sw) * 8]);
}

__device__ __forceinline__ void read_bf2(bf16x8 (&dst)[2][2], const __bf16* p,
                                         int rowBase, int lm, int kq, int sw)
{
#pragma unroll
    for (int j = 0; j < 2; ++j)
#pragma unroll
        for (int h = 0; h < 2; ++h)
            dst[j][h] = *reinterpret_cast<const bf16x8*>(
                &p[(rowBase + j * 16 + lm) * BK2 + ((kq + h * 4) ^ sw) * 8]);
}

__global__ __launch_bounds__(512)
void gemm_fused(const float* __restrict__ X, const int* __restrict__ W,
                const float* __restrict__ scale, const float* __restrict__ bias,
                float* __restrict__ Out, int M, int N, int K)
{
    __shared__ __bf16 sA[2 * ABUF];   // 64 KB
    __shared__ __bf16 sB[2 * ABUF];   // 64 KB

    const int tid  = threadIdx.x;
    const int wave = tid >> 6;
    const int lane = tid & 63;
    const int row0 = blockIdx.y * BM2;
    const int col0 = blockIdx.x * BN2;

    const float* Ab = X + (size_t)row0 * K;
    const int*   Wb = W + (size_t)col0 * K;

#define U_ROW(j) ((tid + (j) * 512) >> 4)
#define U_CB(j)  ((tid + (j) * 512) & 15)

#define LD_CHUNK(set, SRC, h, kt_)                                             \
    do { _Pragma("unroll") for (int j = 0; j < 4; ++j) {                       \
        set[j] = *reinterpret_cast<const int4*>(                               \
            (SRC) + (size_t)((h) * 128 + U_ROW(j)) * K                         \
                  + (size_t)(kt_) * 64 + U_CB(j) * 4);                         \
    } } while (0)

#define LDS_BYTE(j, base2)                                                     \
    ((base2) + U_ROW(j) * 128 + (((U_CB(j) >> 1) ^ (U_ROW(j) & 7)) * 16)       \
             + (U_CB(j) & 1) * 8)

#define WR_CHUNK_A(set, buf, h)                                                \
    do { _Pragma("unroll") for (int j = 0; j < 4; ++j) {                       \
        bf16x4 hv;                                                             \
        hv[0] = (__bf16)__int_as_float(set[j].x);                              \
        hv[1] = (__bf16)__int_as_float(set[j].y);                              \
        hv[2] = (__bf16)__int_as_float(set[j].z);                              \
        hv[3] = (__bf16)__int_as_float(set[j].w);                              \
        *reinterpret_cast<bf16x4*>((char*)sA +                                 \
            LDS_BYTE(j, ((buf) * ABUF + (h) * HALF) * 2)) = hv;                \
    } } while (0)

#define WR_CHUNK_B(set, buf, h)                                                \
    do { _Pragma("unroll") for (int j = 0; j < 4; ++j) {                       \
        bf16x4 hv;                                                             \
        hv[0] = (__bf16)(float)set[j].x;                                       \
        hv[1] = (__bf16)(float)set[j].y;                                       \
        hv[2] = (__bf16)(float)set[j].z;                                       \
        hv[3] = (__bf16)(float)set[j].w;                                       \
        *reinterpret_cast<bf16x4*>((char*)sB +                                 \
            LDS_BYTE(j, ((buf) * ABUF + (h) * HALF) * 2)) = hv;                \
    } } while (0)

    // fragment geometry (identical to v12)
    const int hA  = wave >> 2;
    const int hB  = (wave & 3) >> 1;
    const int wnh = (wave & 1) * 64;
    const int lm  = lane & 15;
    const int kq  = lane >> 4;
    const int sw  = lm & 7;

    const __bf16* aH[2] = { sA + hA * HALF, sA + ABUF + hA * HALF };
    const __bf16* bH[2] = { sB + hB * HALF, sB + ABUF + hB * HALF };

    floatx4 acc[8][4];
#pragma unroll
    for (int i = 0; i < 8; ++i)
#pragma unroll
        for (int j = 0; j < 4; ++j)
            acc[i][j] = (floatx4)0.0f;

    bf16x8 bfA[2][2], bfB[2][2], af[2][2];
    int4 s0[4], s1[4];
    const int nt = K / BK2;   // launcher guarantees even, >= 4

    // --- prologue: A(0), B(0), B(1)h0 synchronous; B(1)h1 left pending (s1)
    LD_CHUNK(s0, Ab, 0, 0); WR_CHUNK_A(s0, 0, 0);
    LD_CHUNK(s0, Ab, 1, 0); WR_CHUNK_A(s0, 0, 1);
    LD_CHUNK(s0, Wb, 0, 0); WR_CHUNK_B(s0, 0, 0);
    LD_CHUNK(s0, Wb, 1, 0); WR_CHUNK_B(s0, 0, 1);
    LD_CHUNK(s0, Wb, 0, 1); WR_CHUNK_B(s0, 1, 0);
    LD_CHUNK(s1, Wb, 1, 1);                          // pending c3 of "tile -1"
    asm volatile("s_waitcnt lgkmcnt(0)" ::: "memory");
    BARRIER();
    read_bf2(bfA, bH[0], wnh, lm, kq, sw);

#define PHASE(Q, c, HEADX, ISSUE, POSTX, WRX)                                  \
    do {                                                                       \
        HEADX;                                                                 \
        read_afH(af, aH[c], (Q) * 32, lm, kq, sw);                             \
        ISSUE;                                                                 \
        BARRIER();                                                             \
        __builtin_amdgcn_sched_barrier(0);                                     \
        __builtin_amdgcn_s_setprio(1);                                         \
        mfma16s<Q>(acc, af, bfA, bfB);                                         \
        __builtin_amdgcn_s_setprio(0);                                         \
        __builtin_amdgcn_sched_barrier(0);                                     \
        POSTX;                                                                 \
        WRX;                                                                   \
        asm volatile("s_waitcnt lgkmcnt(0)" ::: "memory");                     \
        BARRIER();                                                             \
    } while (0)

#define TILE(c, e1, e2)                                                        \
    PHASE(0, c, read_bf2(bfB, bH[c], wnh + 32, lm, kq, sw),                    \
          LD_CHUNK(s0, Ab, 0, e1), (void)0, WR_CHUNK_B(s1, (c) ^ 1, 1));       \
    PHASE(1, c, (void)0, LD_CHUNK(s1, Ab, 1, e1), (void)0,                     \
          WR_CHUNK_A(s0, (c) ^ 1, 0));                                         \
    PHASE(2, c, (void)0, LD_CHUNK(s0, Wb, 0, e2), (void)0,                     \
          WR_CHUNK_A(s1, (c) ^ 1, 1));                                         \
    PHASE(3, c, (void)0, LD_CHUNK(s1, Wb, 1, e2),                              \
          read_bf2(bfA, bH[(c) ^ 1], wnh, lm, kq, sw), WR_CHUNK_B(s0, (c), 0));

    for (int it = 0; it < nt / 2; ++it) {
        const int kt = 2 * it;
        const int e1 = kt + 1;                        // always real (nt even)
        const int e2 = (kt + 2 < nt) ? kt + 2 : 0;    // phantoms land in dead
        const int f2 = (kt + 3 < nt) ? kt + 3 : 0;    //   regions (verified)
        TILE(0, e1, e2)
        TILE(1, e2, f2)
    }
    asm volatile("s_waitcnt vmcnt(0) lgkmcnt(0)" ::: "memory");  // drain phantoms
#undef TILE
#undef PHASE
#undef WR_CHUNK_A
#undef WR_CHUNK_B
#undef LDS_BYTE
#undef LD_CHUNK
#undef U_ROW
#undef U_CB

    // --- epilogue: C/D layout col=lane&15, row=(lane>>4)*4+reg (m89-verified)
    const int wm = hA * 128;
    const int wn = (wave & 3) * 64;
#pragma unroll
    for (int j = 0; j < 4; ++j) {
        int n = col0 + wn + j * 16 + lm;
        float sc = scale[n];
        float bi = bias[n];
#pragma unroll
        for (int i = 0; i < 8; ++i) {
#pragma unroll
            for (int r = 0; r < 4; ++r) {
                int m = row0 + wm + i * 16 + kq * 4 + r;
                Out[(size_t)m * N + n] = sc * acc[i][j][r] + bi;
            }
        }
    }
}

// ---------------------------------------------------------------------------
// Fallback for non-conforming shapes: fused conversion, 128x128, no workspace.
// ---------------------------------------------------------------------------
#define BM 128
#define BN 128

__global__ __launch_bounds__(256)
void fp4linear_gemm(const float* __restrict__ X, const int* __restrict__ W,
                    const float* __restrict__ scale, const float* __restrict__ bias,
                    float* __restrict__ Out, int M, int N, int K)
{
    __shared__ __bf16 sA[BM * 32];
    __shared__ __bf16 sB[BN * 32];

    const int tid  = threadIdx.x;
    const int row0 = blockIdx.y * BM;
    const int col0 = blockIdx.x * BN;
    const int wave = tid >> 6;
    const int lane = tid & 63;
    const int wm = (wave >> 1) * 64;
    const int wn = (wave & 1) * 64;
    const int lm = lane & 15;
    const int kq = lane >> 4;

    floatx4 acc[4][4];
#pragma unroll
    for (int i = 0; i < 4; ++i)
#pragma unroll
        for (int j = 0; j < 4; ++j)
            acc[i][j] = (floatx4)0.0f;

    for (int k0 = 0; k0 < K; k0 += 32) {
        float4 fa[4];
        int4   ib[4];
#pragma unroll
        for (int l = 0; l < 4; ++l) {
            int idx = tid + l * 256;
            int r = idx >> 3, c4 = idx & 7;
            fa[l] = *reinterpret_cast<const float4*>(
                        &X[(size_t)(row0 + r) * K + k0 + c4 * 4]);
        }
#pragma unroll
        for (int l = 0; l < 4; ++l) {
            int idx = tid + l * 256;
            int r = idx >> 3, c4 = idx & 7;
            ib[l] = *reinterpret_cast<const int4*>(
                        &W[(size_t)(col0 + r) * K + k0 + c4 * 4]);
        }
        __syncthreads();
#pragma unroll
        for (int l = 0; l < 4; ++l) {
            int idx = tid + l * 256;
            int r = idx >> 3, c4 = idx & 7;
            bf16x4 h;
            h[0] = (__bf16)fa[l].x; h[1] = (__bf16)fa[l].y;
            h[2] = (__bf16)fa[l].z; h[3] = (__bf16)fa[l].w;
            *reinterpret_cast<bf16x4*>(&sA[r * 32 + c4 * 4]) = h;
        }
#pragma unroll
        for (int l = 0; l < 4; ++l) {
            int idx = tid + l * 256;
            int r = idx >> 3, c4 = idx & 7;
            bf16x4 h;
            h[0] = (__bf16)(float)ib[l].x; h[1] = (__bf16)(float)ib[l].y;
            h[2] = (__bf16)(float)ib[l].z; h[3] = (__bf16)(float)ib[l].w;
            *reinterpret_cast<bf16x4*>(&sB[r * 32 + c4 * 4]) = h;
        }
        __syncthreads();

        bf16x8 af[4], bfr[4];
#pragma unroll
        for (int i = 0; i < 4; ++i)
            af[i] = *reinterpret_cast<const bf16x8*>(
                        &sA[(wm + i * 16 + lm) * 32 + kq * 8]);
#pragma unroll
        for (int j = 0; j < 4; ++j)
            bfr[j] = *reinterpret_cast<const bf16x8*>(
                        &sB[(wn + j * 16 + lm) * 32 + kq * 8]);
#pragma unroll
        for (int i = 0; i < 4; ++i)
#pragma unroll
            for (int j = 0; j < 4; ++j)
                acc[i][j] = __builtin_amdgcn_mfma_f32_16x16x32_bf16(
                                af[i], bfr[j], acc[i][j], 0, 0, 0);
    }

#pragma unroll
    for (int j = 0; j < 4; ++j) {
        int n = col0 + wn + j * 16 + lm;
        float sc = scale[n];
        float bi = bias[n];
#pragma unroll
        for (int i = 0; i < 4; ++i) {
#pragma unroll
            for (int r = 0; r < 4; ++r) {
                int m = row0 + wm + i * 16 + kq * 4 + r;
                Out[(size_t)m * N + n] = sc * acc[i][j][r] + bi;
            }
        }
    }
}

extern "C" void kernel_launch(void* const* d_in, const int* in_sizes, int n_in,
                              void* d_out, int out_size, void* d_ws, size_t ws_size,
                              hipStream_t stream) {
    const float* x     = (const float*)d_in[0];
    const int*   wq    = (const int*)d_in[1];
    const float* scale = (const float*)d_in[2];
    const float* bias  = (const float*)d_in[3];
    float* out = (float*)d_out;

    const int N = in_sizes[2];            // OUT = 4096
    const int K = in_sizes[1] / N;        // IN  = 4096
    const int M = in_sizes[0] / K;        // B*S = 8192

    const int  nt      = K / BK2;
    const bool gemm_ok = (M % BM2 == 0) && (N % BN2 == 0) && (K % BK2 == 0) &&
                         (nt % 2 == 0) && (nt >= 4);

    if (gemm_ok) {
        hipLaunchKernelGGL(gemm_fused, dim3(N / BN2, M / BM2), dim3(512),
                           0, stream, x, wq, scale, bias, out, M, N, K);
        return;
    }

    hipLaunchKernelGGL(fp4linear_gemm, dim3(N / BN, M / BM), dim3(256), 0, stream,
                       x, wq, scale, bias, out, M, N, K);
}